// Round 1
// baseline (158.405 us; speedup 1.0000x reference)
//
#include <hip/hip_runtime.h>
#include <math.h>

// DGCNN forward, algebraically collapsed:
//   out = relu(X_flat @ Meff + const) @ fc2_W + fc2_b
// where Meff (310x64) folds BN-scale, S^2 propagation, lin_W, fc1_W and
// const (64) folds BN-shift, lin_b, fc1_b.
//
// ws layout (floats):
//   [0, 4960)       : per-block BN stat partials (496 blocks x 10)
//   [4960, 24800)   : Meff (310 x 64), 16B-aligned offset
//   [24800, 24864)  : const (64)

#define STATS_BLOCKS 496
#define BN_COUNT 2031616.0f   // B*N = 32768*62

// ---------------------------------------------------------------- K1: BN stats
__global__ __launch_bounds__(256) void k_stats(const float* __restrict__ X,
                                               float* __restrict__ part)
{
    int tid = blockIdx.x * 256 + threadIdx.x;
    const float4* Xv = reinterpret_cast<const float4*>(X) + (size_t)tid * 20;
    float s[5] = {0.f,0.f,0.f,0.f,0.f};
    float q[5] = {0.f,0.f,0.f,0.f,0.f};
#pragma unroll
    for (int v = 0; v < 20; ++v) {
        float4 x = Xv[v];
        s[(4*v+0)%5] += x.x; q[(4*v+0)%5] += x.x*x.x;
        s[(4*v+1)%5] += x.y; q[(4*v+1)%5] += x.y*x.y;
        s[(4*v+2)%5] += x.z; q[(4*v+2)%5] += x.z*x.z;
        s[(4*v+3)%5] += x.w; q[(4*v+3)%5] += x.w*x.w;
    }
#pragma unroll
    for (int k = 0; k < 5; ++k) {
#pragma unroll
        for (int m = 32; m >= 1; m >>= 1) {
            s[k] += __shfl_xor(s[k], m);
            q[k] += __shfl_xor(q[k], m);
        }
    }
    __shared__ float red[4][10];
    int lane = threadIdx.x & 63, w = threadIdx.x >> 6;
    if (lane == 0) {
#pragma unroll
        for (int k = 0; k < 5; ++k) { red[w][k] = s[k]; red[w][5+k] = q[k]; }
    }
    __syncthreads();
    if (threadIdx.x < 10)
        part[blockIdx.x*10 + threadIdx.x] =
            red[0][threadIdx.x] + red[1][threadIdx.x] +
            red[2][threadIdx.x] + red[3][threadIdx.x];
}

// ------------------------------------------------- K2: build Meff + const
// one block per output column o of fc1 (64 blocks x 256 threads)
__global__ __launch_bounds__(256) void k_setup(
    const float* __restrict__ part, const float* __restrict__ edge,
    const float* __restrict__ gamma, const float* __restrict__ beta,
    const float* __restrict__ linW, const float* __restrict__ linb,
    const float* __restrict__ fc1W, const float* __restrict__ fc1b,
    float* __restrict__ Meff, float* __restrict__ constv)
{
    const int o = blockIdx.x;
    const int t = threadIdx.x;
    __shared__ float Amat[62*62];   // W -> A -> L -> S (in place)
    __shared__ float S2m[62*62];    // S @ S
    __shared__ float colo[3968];    // fc1_W[:, o]
    __shared__ float Tm[310];       // T[n*5+f] = sum_h lin_W[f,h] fc1W[n*64+h, o]
    __shared__ float lw[320];
    __shared__ float dv[62];
    __shared__ float dis[62];
    __shared__ float scale[5], shift[5];
    __shared__ float redbuf[256];

    // --- BN stats reduce (all threads) + independent loads before 1st barrier
    {
        float st[10];
#pragma unroll
        for (int k = 0; k < 10; ++k) st[k] = 0.f;
        for (int b = t; b < STATS_BLOCKS; b += 256) {
#pragma unroll
            for (int k = 0; k < 10; ++k) st[k] += part[b*10 + k];
        }
#pragma unroll
        for (int k = 0; k < 10; ++k) {
#pragma unroll
            for (int m = 32; m >= 1; m >>= 1) st[k] += __shfl_xor(st[k], m);
        }
        int lane = t & 63, w = t >> 6;
        if (lane == 0)
            for (int k = 0; k < 10; ++k) redbuf[w*10 + k] = st[k];
    }
    // A = relu(symmetric W from tril params)
    for (int e = t; e < 3844; e += 256) {
        int i = e / 62, j = e % 62;
        int idx = (i >= j) ? (i*(i+1)/2 + j) : (j*(j+1)/2 + i);
        Amat[e] = fmaxf(edge[idx], 0.f);
    }
    for (int i = t; i < 3968; i += 256) colo[i] = fc1W[(size_t)i*64 + o];
    for (int i = t; i < 320;  i += 256) lw[i] = linW[i];
    __syncthreads();

    if (t < 10)
        redbuf[64 + t] = redbuf[t] + redbuf[10+t] + redbuf[20+t] + redbuf[30+t];
    __syncthreads();
    if (t < 5) {
        float mean = redbuf[64 + t] * (1.0f / BN_COUNT);
        float var  = redbuf[69 + t] * (1.0f / BN_COUNT) - mean*mean;
        float inv  = 1.0f / sqrtf(var + 1e-5f);
        scale[t] = gamma[t] * inv;
        shift[t] = beta[t] - mean * gamma[t] * inv;
    }
    // d^{-1/2} of A (row sums incl diagonal)
    if (t < 62) {
        float sum = 0.f;
        for (int j = 0; j < 62; ++j) sum += Amat[t*62 + j];
        dv[t] = 1.0f / sqrtf(sum + 1e-10f);
    }
    __syncthreads();
    // L = dinv_i * A * dinv_j
    for (int e = t; e < 3844; e += 256) {
        int i = e / 62, j = e % 62;
        Amat[e] *= dv[i] * dv[j];
    }
    __syncthreads();
    // deg = 1 + row-sum |L|; dis = deg^{-1/2}
    if (t < 62) {
        float deg = 1.0f;
        for (int j = 0; j < 62; ++j) deg += fabsf(Amat[t*62 + j]);
        dis[t] = 1.0f / sqrtf(deg);
    }
    __syncthreads();
    // S = dis_i (L + I) dis_j
    for (int e = t; e < 3844; e += 256) {
        int i = e / 62, j = e % 62;
        float v = Amat[e] + ((i == j) ? 1.0f : 0.0f);
        Amat[e] = dis[i] * v * dis[j];
    }
    __syncthreads();
    // S2 = S @ S
    for (int e = t; e < 3844; e += 256) {
        int i = e / 62, j = e % 62;
        float sum = 0.f;
        for (int k = 0; k < 62; ++k) sum += Amat[i*62 + k] * Amat[k*62 + j];
        S2m[e] = sum;
    }
    __syncthreads();
    // T[n,f] = sum_h lin_W[f,h] * fc1W[n*64+h, o]
    for (int p = t; p < 310; p += 256) {
        int n = p / 5, f = p % 5;
        float sum = 0.f;
        for (int h = 0; h < 64; ++h) sum += lw[f*64 + h] * colo[n*64 + h];
        Tm[p] = sum;
    }
    __syncthreads();
    // M[j,f] = sum_n S2[n,j] T[n,f];  Meff = scale[f]*M; const partials
    float cpart = 0.f;
    for (int p = t; p < 310; p += 256) {
        int j = p / 5, f = p % 5;
        float m = 0.f;
        for (int n = 0; n < 62; ++n) m += S2m[n*62 + j] * Tm[n*5 + f];
        Meff[(size_t)p*64 + o] = scale[f] * m;
        cpart += shift[f] * m;
    }
    for (int nh = t; nh < 3968; nh += 256)
        cpart += linb[nh & 63] * colo[nh];
    __syncthreads();
    redbuf[t] = cpart;
    __syncthreads();
    for (int sft = 128; sft > 0; sft >>= 1) {
        if (t < sft) redbuf[t] += redbuf[t + sft];
        __syncthreads();
    }
    if (t == 0) constv[o] = redbuf[0] + fc1b[o];
}

// ------------------------------------------- K3: fused GEMM + relu + fc2
// 512 blocks x 256 threads; block = 64 rows, all 64 cols; 5 chunks of 62 j's
__global__ __launch_bounds__(256) void k_gemm(
    const float* __restrict__ X, const float* __restrict__ Meff,
    const float* __restrict__ constv, const float* __restrict__ fc2W,
    const float* __restrict__ fc2b, float* __restrict__ out)
{
    __shared__ float Ms[62*64];     // Meff chunk, [u][o]
    __shared__ float Xs[62*68];     // X chunk transposed, [u][row] pad 64->68
    __shared__ float cst[64];
    __shared__ float f2[192];
    const int t = threadIdx.x;
    const int row0 = blockIdx.x * 64;
    const int tc = t & 15;          // col block: cols tc*4..tc*4+3
    const int tr = t >> 4;          // row block: rows tr*4..tr*4+3
    float acc[4][4];
#pragma unroll
    for (int a = 0; a < 4; ++a)
#pragma unroll
        for (int b = 0; b < 4; ++b) acc[a][b] = 0.f;

    if (t < 64)       cst[t]      = constv[t];
    else if (t < 256) { if (t - 64 < 192) f2[t - 64] = fc2W[t - 64]; }

    const int r  = t >> 2;          // staging: this thread's row
    const int qt = t & 3;           // staging: quarter of the 62 u's
    const int u0 = qt * 16;
    const int ulim = (qt == 3) ? 14 : 16;

    for (int c = 0; c < 5; ++c) {
        __syncthreads();            // previous compute done before overwrite
        // stage Meff chunk (contiguous, float4)
        const float4* msrc = reinterpret_cast<const float4*>(Meff + c*3968);
        float4* mdst = reinterpret_cast<float4*>(Ms);
        for (int i = t; i < 992; i += 256) mdst[i] = msrc[i];
        // stage X chunk, transposed into Xs[u][row]
        const float* xrow = X + (size_t)(row0 + r)*310 + c*62 + u0;
#pragma unroll
        for (int uu = 0; uu < 16; uu += 2) {
            if (uu < ulim) {
                float2 v = *reinterpret_cast<const float2*>(xrow + uu);
                Xs[(u0 + uu    )*68 + r] = v.x;
                Xs[(u0 + uu + 1)*68 + r] = v.y;
            }
        }
        __syncthreads();
        // rank-1 accumulate over the 62 u's of this chunk
#pragma unroll 2
        for (int u = 0; u < 62; ++u) {
            float4 xv = *reinterpret_cast<const float4*>(Xs + u*68 + tr*4);
            float4 mv = *reinterpret_cast<const float4*>(Ms + u*64 + tc*4);
            acc[0][0] += xv.x*mv.x; acc[0][1] += xv.x*mv.y; acc[0][2] += xv.x*mv.z; acc[0][3] += xv.x*mv.w;
            acc[1][0] += xv.y*mv.x; acc[1][1] += xv.y*mv.y; acc[1][2] += xv.y*mv.z; acc[1][3] += xv.y*mv.w;
            acc[2][0] += xv.z*mv.x; acc[2][1] += xv.z*mv.y; acc[2][2] += xv.z*mv.z; acc[2][3] += xv.z*mv.w;
            acc[3][0] += xv.w*mv.x; acc[3][1] += xv.w*mv.y; acc[3][2] += xv.w*mv.z; acc[3][3] += xv.w*mv.w;
        }
    }

    // epilogue: +const, relu, x fc2 (64x3), reduce over the 16 col-threads
    float prt[4][3];
#pragma unroll
    for (int qq = 0; qq < 4; ++qq) { prt[qq][0] = prt[qq][1] = prt[qq][2] = 0.f; }
#pragma unroll
    for (int qq = 0; qq < 4; ++qq) {
#pragma unroll
        for (int p = 0; p < 4; ++p) {
            int col = tc*4 + p;
            float z = fmaxf(acc[qq][p] + cst[col], 0.f);
            prt[qq][0] += z * f2[col*3 + 0];
            prt[qq][1] += z * f2[col*3 + 1];
            prt[qq][2] += z * f2[col*3 + 2];
        }
    }
#pragma unroll
    for (int m = 1; m < 16; m <<= 1) {
#pragma unroll
        for (int qq = 0; qq < 4; ++qq) {
            prt[qq][0] += __shfl_xor(prt[qq][0], m);
            prt[qq][1] += __shfl_xor(prt[qq][1], m);
            prt[qq][2] += __shfl_xor(prt[qq][2], m);
        }
    }
    if (tc == 0) {
        float b0 = fc2b[0], b1 = fc2b[1], b2 = fc2b[2];
#pragma unroll
        for (int qq = 0; qq < 4; ++qq) {
            size_t rw = (size_t)(row0 + tr*4 + qq) * 3;
            out[rw + 0] = prt[qq][0] + b0;
            out[rw + 1] = prt[qq][1] + b1;
            out[rw + 2] = prt[qq][2] + b2;
        }
    }
}

extern "C" void kernel_launch(void* const* d_in, const int* in_sizes, int n_in,
                              void* d_out, int out_size, void* d_ws, size_t ws_size,
                              hipStream_t stream)
{
    const float* X     = (const float*)d_in[0];
    const float* edge  = (const float*)d_in[1];
    const float* gamma = (const float*)d_in[2];
    const float* beta  = (const float*)d_in[3];
    const float* linW  = (const float*)d_in[4];
    const float* linb  = (const float*)d_in[5];
    const float* fc1W  = (const float*)d_in[6];
    const float* fc1b  = (const float*)d_in[7];
    const float* fc2W  = (const float*)d_in[8];
    const float* fc2b  = (const float*)d_in[9];
    float* out = (float*)d_out;
    float* ws  = (float*)d_ws;

    float* part   = ws;            // 496*10 floats
    float* Meff   = ws + 4960;     // 310*64 floats (byte offset 19840, 16B-aligned)
    float* constv = ws + 24800;    // 64 floats

    hipLaunchKernelGGL(k_stats, dim3(496), dim3(256), 0, stream, X, part);
    hipLaunchKernelGGL(k_setup, dim3(64), dim3(256), 0, stream,
                       part, edge, gamma, beta, linW, linb, fc1W, fc1b, Meff, constv);
    hipLaunchKernelGGL(k_gemm, dim3(512), dim3(256), 0, stream,
                       X, Meff, constv, fc2W, fc2b, out);
}